// Round 2
// baseline (1042.806 us; speedup 1.0000x reference)
//
#include <hip/hip_runtime.h>
#include <hip/hip_bf16.h>

#define DEV __device__ __forceinline__

using short8  = __attribute__((ext_vector_type(8))) short;
using ushort8 = __attribute__((ext_vector_type(8))) unsigned short;
using ushort4v= __attribute__((ext_vector_type(4))) unsigned short;
using f32x4   = __attribute__((ext_vector_type(4))) float;

typedef unsigned short ushort_t;

constexpr int B_ = 32, N_ = 512, E_ = 4, D_ = 128;
constexpr int NE = N_ * E_;        // 2048
constexpr int M_TOT = B_ * N_;     // 16384
constexpr int STEPS_ = 5;

// ---------- helpers ----------
DEV ushort_t f2bf(float x) {
    union { float f; unsigned int u; } v; v.f = x;
    unsigned int r = v.u + 0x7FFFu + ((v.u >> 16) & 1u);
    return (ushort_t)(r >> 16);
}

DEV float sigmoidf_(float x) { return 1.0f / (1.0f + __expf(-x)); }

// async global->LDS staging, 16B per lane per issue. LDS layout is LINEAR
// [ROWS][BK] in row-major chunk order (global_load_lds writes wave-uniform
// base + lane*16 — no padding possible, m104/m173).
template<int ROWS, int BK>
DEV void stage_lds(const ushort_t* __restrict__ g, int ld, ushort_t* lds, int tid) {
    constexpr int CPR = BK / 8;            // 16B chunks per row
    constexpr int TOT = ROWS * CPR;
    static_assert(TOT % 256 == 0, "tile not multiple of 256 chunks");
    int w = tid >> 6, lane = tid & 63;
#pragma unroll
    for (int c0 = 0; c0 < TOT; c0 += 256) {
        int c  = c0 + (w << 6) + lane;
        int r  = c / CPR;
        int cc = c % CPR;
        __builtin_amdgcn_global_load_lds(
            (__attribute__((address_space(1))) void*)(g + r * ld + cc * 8),
            (__attribute__((address_space(3))) void*)(lds + (c0 + (w << 6)) * 8),
            16, 0, 0);
    }
}

// MFMA over one K-step. LDS layouts: lA [BM][LDT] (row=m), lB [BN][LDT] (row=n i.e. B^T)
template<int BM, int BN, int BK, int LDT>
DEV void mma(const ushort_t* lA, const ushort_t* lB,
             f32x4 (&acc)[BM/32][BN/32], int wm, int wn, int l15, int lg) {
    constexpr int MF = BM / 32, NF = BN / 32;
#pragma unroll
    for (int kk = 0; kk < BK / 32; ++kk) {
        short8 a[MF], b[NF];
#pragma unroll
        for (int i = 0; i < MF; ++i)
            a[i] = *reinterpret_cast<const short8*>(lA + (wm*(BM/2) + i*16 + l15)*LDT + kk*32 + lg*8);
#pragma unroll
        for (int j = 0; j < NF; ++j)
            b[j] = *reinterpret_cast<const short8*>(lB + (wn*(BN/2) + j*16 + l15)*LDT + kk*32 + lg*8);
#pragma unroll
        for (int i = 0; i < MF; ++i)
#pragma unroll
            for (int j = 0; j < NF; ++j)
                acc[i][j] = __builtin_amdgcn_mfma_f32_16x16x32_bf16(a[i], b[j], acc[i][j], 0, 0, 0);
    }
}

// ---------- prep kernels ----------
__global__ __launch_bounds__(256) void convertA(const float* __restrict__ A, ushort_t* __restrict__ Abf) {
    const long long TOT8 = (long long)B_ * N_ * 2 * NE / 8;  // 8,388,608
    for (long long i = blockIdx.x * 256ll + threadIdx.x; i < TOT8; i += (long long)gridDim.x * 256ll) {
        float4 v0 = reinterpret_cast<const float4*>(A)[2*i];
        float4 v1 = reinterpret_cast<const float4*>(A)[2*i+1];
        ushort8 r;
        r[0]=f2bf(v0.x); r[1]=f2bf(v0.y); r[2]=f2bf(v0.z); r[3]=f2bf(v0.w);
        r[4]=f2bf(v1.x); r[5]=f2bf(v1.y); r[6]=f2bf(v1.z); r[7]=f2bf(v1.w);
        *reinterpret_cast<ushort8*>(Abf + 8*i) = r;
    }
}

__global__ __launch_bounds__(256) void prep_weights(
    const float* __restrict__ in_W, const float* __restrict__ out_W,
    const float* __restrict__ rW, const float* __restrict__ zW,
    const float* __restrict__ tW, const float* __restrict__ oW,
    ushort_t* WinT, ushort_t* WoutT, ushort_t* WrzT, ushort_t* WtT, ushort_t* WoT) {
    int idx = blockIdx.x * 256 + threadIdx.x;
    if (idx < 65536) {  // WinT/WoutT[e][h_out][d_k] = W[e][d_k][h_out]
        int e = idx >> 14, j = (idx >> 7) & 127, k = idx & 127;
        WinT[idx]  = f2bf(in_W [(e<<14) + (k<<7) + j]);
        WoutT[idx] = f2bf(out_W[(e<<14) + (k<<7) + j]);
        return;
    }
    idx -= 65536;
    if (idx < 98304) {  // WrzT[j][k], j<128 -> rW cols, else zW cols
        int j = idx / 384, k = idx % 384;
        WrzT[idx] = f2bf(j < 128 ? rW[k*128 + j] : zW[k*128 + (j-128)]);
        return;
    }
    idx -= 98304;
    if (idx < 49152) {  // WtT[j][k] = tW[k][j]
        int j = idx / 384, k = idx % 384;
        WtT[idx] = f2bf(tW[k*128 + j]);
        return;
    }
    idx -= 49152;
    if (idx < 32768) {  // WoT[j][k] = oW[k][j], k<256
        int j = idx / 256, k = idx % 256;
        WoT[idx] = f2bf(oW[k*128 + j]);
        return;
    }
}

__global__ __launch_bounds__(256) void initState(const float* __restrict__ p,
                                                 float* __restrict__ sf,
                                                 ushort_t* __restrict__ sb,
                                                 ushort_t* __restrict__ ib) {
    int i = blockIdx.x * 256 + threadIdx.x;       // grid covers 2M/4 float4s
    float4 v = reinterpret_cast<const float4*>(p)[i];
    reinterpret_cast<float4*>(sf)[i] = v;
    ushort4v r; r[0]=f2bf(v.x); r[1]=f2bf(v.y); r[2]=f2bf(v.z); r[3]=f2bf(v.w);
    *reinterpret_cast<ushort4v*>(sb + 4*i) = r;
    *reinterpret_cast<ushort4v*>(ib + 4*i) = r;
}

// ---------- step kernels ----------
// proj: in/out_states[b, e*N+n, h] = state[b,n,:] @ W[e] + b[e]; written TRANSPOSED: S_T[b][h][e*N+n]
__global__ __launch_bounds__(256) void proj_kernel(
    const ushort_t* __restrict__ state_bf, const ushort_t* __restrict__ WinT,
    const ushort_t* __restrict__ WoutT, const float* __restrict__ in_b,
    const float* __restrict__ out_b, ushort_t* __restrict__ SinT, ushort_t* __restrict__ SoutT) {
    __shared__ alignas(16) ushort_t lA[128 * 136];  // staged linear [128][128]; epilogue pitch 136
    __shared__ alignas(16) ushort_t lB[128 * 128];
    int tid = threadIdx.x, w = tid >> 6, l15 = tid & 15, lg = (tid & 63) >> 4;
    int wm = w >> 1, wn = w & 1;
    int bid = blockIdx.x;
    int mt = bid & 3, io = (bid >> 2) & 1, e = (bid >> 3) & 3, b = bid >> 5;

    const ushort_t* Asrc = state_bf + (b * N_ + mt * 128) * D_;
    const ushort_t* Bsrc = (io ? WoutT : WinT) + e * D_ * D_;
    const float* bias = (io ? out_b : in_b) + e * D_;
    ushort_t* Out = (io ? SoutT : SinT) + (size_t)b * D_ * NE;

    stage_lds<128, 128>(Asrc, D_, lA, tid);
    stage_lds<128, 128>(Bsrc, D_, lB, tid);
    __syncthreads();
    f32x4 acc[4][4] = {};
    mma<128, 128, 128, 128>(lA, lB, acc, wm, wn, l15, lg);
    __syncthreads();
    // transpose into lA with pitch 136 (pad avoids 16-way write conflict): lA[h][n]
#pragma unroll
    for (int j = 0; j < 4; ++j) {
        int d = wn * 64 + j * 16 + l15;
        float bv = bias[d];
#pragma unroll
        for (int i = 0; i < 4; ++i)
#pragma unroll
            for (int q = 0; q < 4; ++q) {
                int n = wm * 64 + i * 16 + lg * 4 + q;
                lA[d * 136 + n] = f2bf(acc[i][j][q] + bv);
            }
    }
    __syncthreads();
    int d = tid >> 1, half = tid & 1;
    const ushort_t* srcL = lA + d * 136 + half * 64;
    ushort_t* dstG = Out + (size_t)d * NE + e * N_ + mt * 128 + half * 64;
#pragma unroll
    for (int i = 0; i < 8; ++i)
        *reinterpret_cast<uint4*>(dstG + i * 8) = *reinterpret_cast<const uint4*>(srcL + i * 8);
}

// bigA: a_io[b, n, d] = A_bf[b, n, io*NE + m] @ S_ioT[b][d][m]   (K = 2048)
__global__ __launch_bounds__(256) void bigA_kernel(
    const ushort_t* __restrict__ A_bf, const ushort_t* __restrict__ SinT,
    const ushort_t* __restrict__ SoutT, ushort_t* __restrict__ a_in_bf, ushort_t* __restrict__ a_out_bf) {
    __shared__ alignas(16) ushort_t lA[64 * 128];
    __shared__ alignas(16) ushort_t lB[128 * 128];
    int tid = threadIdx.x, w = tid >> 6, l15 = tid & 15, lg = (tid & 63) >> 4;
    int wm = w >> 1, wn = w & 1;
    // XCD swizzle: grid=512, 8 XCDs; give each XCD 64 consecutive work items so
    // the 8 blocks sharing one (b,io) B-panel co-reside in one XCD L2 (4MB = 8 panels).
    int bid = (blockIdx.x & 7) * 64 + (blockIdx.x >> 3);
    int mt = bid & 7, io = (bid >> 3) & 1, b = bid >> 4;

    const ushort_t* Asrc = A_bf + (size_t)b * N_ * 2 * NE + (size_t)(mt * 64) * (2 * NE) + io * NE;
    const ushort_t* Bsrc = (io ? SoutT : SinT) + (size_t)b * D_ * NE;
    ushort_t* Out = (io ? a_out_bf : a_in_bf) + (size_t)(b * N_ + mt * 64) * D_;

    f32x4 acc[2][4] = {};
    for (int k0 = 0; k0 < NE; k0 += 128) {
        stage_lds<64, 128>(Asrc + k0, 2 * NE, lA, tid);
        stage_lds<128, 128>(Bsrc + k0, NE, lB, tid);
        __syncthreads();
        mma<64, 128, 128, 128>(lA, lB, acc, wm, wn, l15, lg);
        __syncthreads();
    }
#pragma unroll
    for (int j = 0; j < 4; ++j) {
        int col = wn * 64 + j * 16 + l15;
#pragma unroll
        for (int i = 0; i < 2; ++i)
#pragma unroll
            for (int q = 0; q < 4; ++q) {
                int row = wm * 32 + i * 16 + lg * 4 + q;
                Out[row * D_ + col] = f2bf(acc[i][j][q]);
            }
    }
}

// rz: preact = [a_in|a_out|state] @ [rW|zW]  (K=384, N=256 split in two col-blocks)
__global__ __launch_bounds__(256) void rz_kernel(
    const ushort_t* __restrict__ a_in_bf, const ushort_t* __restrict__ a_out_bf,
    const ushort_t* __restrict__ state_bf, const ushort_t* __restrict__ WrzT,
    const float* __restrict__ rb, const float* __restrict__ zb,
    const float* __restrict__ state_f32, ushort_t* __restrict__ rs_bf, float* __restrict__ z_f32) {
    __shared__ alignas(16) ushort_t lA[128 * 128];
    __shared__ alignas(16) ushort_t lB[128 * 128];
    int tid = threadIdx.x, w = tid >> 6, l15 = tid & 15, lg = (tid & 63) >> 4;
    int wm = w >> 1, wn = w & 1;
    int mt = blockIdx.x >> 1, cb = blockIdx.x & 1;

    const ushort_t* srcs[3] = { a_in_bf + (size_t)mt * 128 * D_,
                                a_out_bf + (size_t)mt * 128 * D_,
                                state_bf + (size_t)mt * 128 * D_ };
    const ushort_t* Bsrc = WrzT + (size_t)cb * 128 * 384;

    f32x4 acc[4][4] = {};
    for (int ks = 0; ks < 3; ++ks) {
        stage_lds<128, 128>(srcs[ks], D_, lA, tid);
        stage_lds<128, 128>(Bsrc + ks * 128, 384, lB, tid);
        __syncthreads();
        mma<128, 128, 128, 128>(lA, lB, acc, wm, wn, l15, lg);
        __syncthreads();
    }
    if (cb == 0) {
#pragma unroll
        for (int j = 0; j < 4; ++j) {
            int col = wn * 64 + j * 16 + l15;
            float bv = rb[col];
#pragma unroll
            for (int i = 0; i < 4; ++i)
#pragma unroll
                for (int q = 0; q < 4; ++q) {
                    int row = mt * 128 + wm * 64 + i * 16 + lg * 4 + q;
                    float r = sigmoidf_(acc[i][j][q] + bv);
                    float s = state_f32[(size_t)row * D_ + col];
                    rs_bf[(size_t)row * D_ + col] = f2bf(r * s);
                }
        }
    } else {
#pragma unroll
        for (int j = 0; j < 4; ++j) {
            int col = wn * 64 + j * 16 + l15;
            float bv = zb[col];
#pragma unroll
            for (int i = 0; i < 4; ++i)
#pragma unroll
                for (int q = 0; q < 4; ++q) {
                    int row = mt * 128 + wm * 64 + i * 16 + lg * 4 + q;
                    z_f32[(size_t)row * D_ + col] = sigmoidf_(acc[i][j][q] + bv);
                }
        }
    }
}

// t: h = tanh([a_in|a_out|r*state] @ tW + tb); state = (1-z)*state + z*h
__global__ __launch_bounds__(256) void t_kernel(
    const ushort_t* __restrict__ a_in_bf, const ushort_t* __restrict__ a_out_bf,
    const ushort_t* __restrict__ rs_bf, const ushort_t* __restrict__ WtT,
    const float* __restrict__ tb, const float* __restrict__ z_f32,
    float* __restrict__ state_f32, ushort_t* __restrict__ state_bf) {
    __shared__ alignas(16) ushort_t lA[128 * 128];
    __shared__ alignas(16) ushort_t lB[128 * 128];
    int tid = threadIdx.x, w = tid >> 6, l15 = tid & 15, lg = (tid & 63) >> 4;
    int wm = w >> 1, wn = w & 1;
    int mt = blockIdx.x;

    const ushort_t* srcs[3] = { a_in_bf + (size_t)mt * 128 * D_,
                                a_out_bf + (size_t)mt * 128 * D_,
                                rs_bf + (size_t)mt * 128 * D_ };
    f32x4 acc[4][4] = {};
    for (int ks = 0; ks < 3; ++ks) {
        stage_lds<128, 128>(srcs[ks], D_, lA, tid);
        stage_lds<128, 128>(WtT + ks * 128, 384, lB, tid);
        __syncthreads();
        mma<128, 128, 128, 128>(lA, lB, acc, wm, wn, l15, lg);
        __syncthreads();
    }
#pragma unroll
    for (int j = 0; j < 4; ++j) {
        int col = wn * 64 + j * 16 + l15;
        float bv = tb[col];
#pragma unroll
        for (int i = 0; i < 4; ++i)
#pragma unroll
            for (int q = 0; q < 4; ++q) {
                int row = mt * 128 + wm * 64 + i * 16 + lg * 4 + q;
                size_t idx = (size_t)row * D_ + col;
                float h = tanhf(acc[i][j][q] + bv);
                float z = z_f32[idx];
                float s = state_f32[idx];
                float ns = (1.0f - z) * s + z * h;
                state_f32[idx] = ns;
                state_bf[idx] = f2bf(ns);
            }
    }
}

// final: out = tanh([state|init] @ oW + ob)
__global__ __launch_bounds__(256) void final_kernel(
    const ushort_t* __restrict__ state_bf, const ushort_t* __restrict__ init_bf,
    const ushort_t* __restrict__ WoT, const float* __restrict__ ob, float* __restrict__ out) {
    __shared__ alignas(16) ushort_t lA[128 * 128];
    __shared__ alignas(16) ushort_t lB[128 * 128];
    int tid = threadIdx.x, w = tid >> 6, l15 = tid & 15, lg = (tid & 63) >> 4;
    int wm = w >> 1, wn = w & 1;
    int mt = blockIdx.x;

    const ushort_t* srcs[2] = { state_bf + (size_t)mt * 128 * D_,
                                init_bf + (size_t)mt * 128 * D_ };
    f32x4 acc[4][4] = {};
    for (int ks = 0; ks < 2; ++ks) {
        stage_lds<128, 128>(srcs[ks], D_, lA, tid);
        stage_lds<128, 128>(WoT + ks * 128, 256, lB, tid);
        __syncthreads();
        mma<128, 128, 128, 128>(lA, lB, acc, wm, wn, l15, lg);
        __syncthreads();
    }
#pragma unroll
    for (int j = 0; j < 4; ++j) {
        int col = wn * 64 + j * 16 + l15;
        float bv = ob[col];
#pragma unroll
        for (int i = 0; i < 4; ++i)
#pragma unroll
            for (int q = 0; q < 4; ++q) {
                int row = mt * 128 + wm * 64 + i * 16 + lg * 4 + q;
                out[(size_t)row * D_ + col] = tanhf(acc[i][j][q] + bv);
            }
    }
}

// ---------- launch ----------
extern "C" void kernel_launch(void* const* d_in, const int* in_sizes, int n_in,
                              void* d_out, int out_size, void* d_ws, size_t ws_size,
                              hipStream_t stream) {
    const float* prop  = (const float*)d_in[0];
    const float* A     = (const float*)d_in[1];
    const float* in_W  = (const float*)d_in[3];
    const float* in_b  = (const float*)d_in[4];
    const float* out_W = (const float*)d_in[5];
    const float* out_b = (const float*)d_in[6];
    const float* rW    = (const float*)d_in[7];
    const float* rb    = (const float*)d_in[8];
    const float* zW    = (const float*)d_in[9];
    const float* zb    = (const float*)d_in[10];
    const float* tW    = (const float*)d_in[11];
    const float* tb    = (const float*)d_in[12];
    const float* oW    = (const float*)d_in[13];
    const float* ob    = (const float*)d_in[14];
    float* outp = (float*)d_out;

    size_t off = 0;
    auto carve = [&](size_t bytes) {
        void* p = (char*)d_ws + off;
        off += (bytes + 255) & ~(size_t)255;
        return p;
    };
    ushort_t* A_bf     = (ushort_t*)carve((size_t)B_*N_*2*NE*2);   // 128 MiB
    ushort_t* SinT     = (ushort_t*)carve((size_t)B_*D_*NE*2);     // 16 MiB
    ushort_t* SoutT    = (ushort_t*)carve((size_t)B_*D_*NE*2);
    ushort_t* a_in_bf  = (ushort_t*)carve((size_t)M_TOT*D_*2);
    ushort_t* a_out_bf = (ushort_t*)carve((size_t)M_TOT*D_*2);
    ushort_t* rs_bf    = (ushort_t*)carve((size_t)M_TOT*D_*2);
    ushort_t* state_bf = (ushort_t*)carve((size_t)M_TOT*D_*2);
    ushort_t* init_bf  = (ushort_t*)carve((size_t)M_TOT*D_*2);
    float*    state_f32= (float*)carve((size_t)M_TOT*D_*4);
    float*    z_f32    = (float*)carve((size_t)M_TOT*D_*4);
    ushort_t* WinT     = (ushort_t*)carve((size_t)E_*D_*D_*2);
    ushort_t* WoutT    = (ushort_t*)carve((size_t)E_*D_*D_*2);
    ushort_t* WrzT     = (ushort_t*)carve((size_t)256*384*2);
    ushort_t* WtT      = (ushort_t*)carve((size_t)128*384*2);
    ushort_t* WoT      = (ushort_t*)carve((size_t)128*256*2);
    (void)ws_size; (void)n_in; (void)in_sizes; (void)out_size;

    convertA<<<4096, 256, 0, stream>>>(A, A_bf);
    prep_weights<<<960, 256, 0, stream>>>(in_W, out_W, rW, zW, tW, oW, WinT, WoutT, WrzT, WtT, WoT);
    initState<<<2048, 256, 0, stream>>>(prop, state_f32, state_bf, init_bf);

    for (int s = 0; s < STEPS_; ++s) {
        proj_kernel<<<1024, 256, 0, stream>>>(state_bf, WinT, WoutT, in_b, out_b, SinT, SoutT);
        bigA_kernel<<<512, 256, 0, stream>>>(A_bf, SinT, SoutT, a_in_bf, a_out_bf);
        rz_kernel<<<256, 256, 0, stream>>>(a_in_bf, a_out_bf, state_bf, WrzT, rb, zb,
                                           state_f32, rs_bf, z_f32);
        t_kernel<<<128, 256, 0, stream>>>(a_in_bf, a_out_bf, rs_bf, WtT, tb, z_f32,
                                          state_f32, state_bf);
    }
    final_kernel<<<128, 256, 0, stream>>>(state_bf, init_bf, WoT, ob, outp);
}

// Round 4
// 998.913 us; speedup vs baseline: 1.0439x; 1.0439x over previous
//
#include <hip/hip_runtime.h>

#define DEV __device__ __forceinline__

using half8   = __attribute__((ext_vector_type(8))) _Float16;
using ushort8 = __attribute__((ext_vector_type(8))) unsigned short;
using f32x4   = __attribute__((ext_vector_type(4))) float;

typedef unsigned short ushort_t;

constexpr int B_ = 32, N_ = 512, E_ = 4, D_ = 128;
constexpr int NE = N_ * E_;        // 2048
constexpr int M_TOT = B_ * N_;     // 16384
constexpr int STEPS_ = 5;

// ---------- helpers ----------
DEV ushort_t f2h(float x) { union { _Float16 h; ushort_t u; } v; v.h = (_Float16)x; return v.u; }
DEV float sigmoidf_(float x) { return 1.0f / (1.0f + __expf(-x)); }

// async global->LDS staging of ROWS x 64 f16 tile (BK=64). LDS linear [ROWS][64].
template<int ROWS>
DEV void stage64(const ushort_t* __restrict__ g, int ld, ushort_t* lds, int tid) {
    constexpr int TOT = ROWS * 8;          // 16B chunks (8 per row)
    static_assert(TOT % 256 == 0, "");
    int w = tid >> 6, lane = tid & 63;
#pragma unroll
    for (int c0 = 0; c0 < TOT; c0 += 256) {
        int c  = c0 + (w << 6) + lane;
        int r  = c >> 3;
        int cc = c & 7;
        __builtin_amdgcn_global_load_lds(
            (__attribute__((address_space(1))) void*)(g + r * ld + cc * 8),
            (__attribute__((address_space(3))) void*)(lds + (c0 + (w << 6)) * 8),
            16, 0, 0);
    }
}

// one BK=64 K-step. lA [BM][64] rows=m, lB [BN][64] rows=n (B^T). 4 waves: 2x2.
template<int BM, int BN>
DEV void mma64(const ushort_t* lA, const ushort_t* lB,
               f32x4 (&acc)[BM/32][BN/32], int wm, int wn, int l15, int lg) {
    constexpr int MF = BM / 32, NF = BN / 32;
#pragma unroll
    for (int kk = 0; kk < 2; ++kk) {
        half8 a[MF], b[NF];
#pragma unroll
        for (int i = 0; i < MF; ++i)
            a[i] = *reinterpret_cast<const half8*>(lA + (wm*(BM/2) + i*16 + l15)*64 + kk*32 + lg*8);
#pragma unroll
        for (int j = 0; j < NF; ++j)
            b[j] = *reinterpret_cast<const half8*>(lB + (wn*(BN/2) + j*16 + l15)*64 + kk*32 + lg*8);
#pragma unroll
        for (int i = 0; i < MF; ++i)
#pragma unroll
            for (int j = 0; j < NF; ++j)
                acc[i][j] = __builtin_amdgcn_mfma_f32_16x16x32_f16(a[i], b[j], acc[i][j], 0, 0, 0);
    }
}

// ---------- prep ----------
// convert A -> f16 AND per-(row, io, e) rowsums in fp32. One block per row (16384).
__global__ __launch_bounds__(256) void convertA_rs(const float* __restrict__ A,
                                                   ushort_t* __restrict__ A_h,
                                                   float* __restrict__ Ars) {
    int row = blockIdx.x, t = threadIdx.x;
    const float* src = A + (size_t)row * 4096 + t * 16;
    ushort_t* dst = A_h + (size_t)row * 4096 + t * 16;
    float s = 0.f;
#pragma unroll
    for (int c = 0; c < 2; ++c) {
        float4 v0 = reinterpret_cast<const float4*>(src)[2*c];
        float4 v1 = reinterpret_cast<const float4*>(src)[2*c+1];
        s += v0.x+v0.y+v0.z+v0.w + v1.x+v1.y+v1.z+v1.w;
        ushort8 r;
        r[0]=f2h(v0.x); r[1]=f2h(v0.y); r[2]=f2h(v0.z); r[3]=f2h(v0.w);
        r[4]=f2h(v1.x); r[5]=f2h(v1.y); r[6]=f2h(v1.z); r[7]=f2h(v1.w);
        *reinterpret_cast<ushort8*>(dst + 8*c) = r;
    }
    // segment = t/32 (512 cols per (io,e) segment); reduce across the 32 lanes
#pragma unroll
    for (int m = 16; m; m >>= 1) s += __shfl_xor(s, m);
    if ((t & 31) == 0) Ars[(size_t)row * 8 + (t >> 5)] = s;
}

__global__ __launch_bounds__(256) void prep_weights(
    const float* __restrict__ in_W, const float* __restrict__ out_W,
    const float* __restrict__ rW, const float* __restrict__ zW,
    const float* __restrict__ tW, const float* __restrict__ oW,
    ushort_t* WstT, ushort_t* WrzT, ushort_t* WtT, ushort_t* WoT) {
    int idx = blockIdx.x * 256 + threadIdx.x;
    if (idx < 131072) {  // WstT[io][d][e*128+h] = W_io[e][h][d]
        int io = idx >> 16, r = idx & 65535, d = r >> 9, eh = r & 511, e = eh >> 7, h = eh & 127;
        const float* W = io ? out_W : in_W;
        WstT[idx] = f2h(W[e*16384 + h*128 + d]);
        return;
    }
    idx -= 131072;
    if (idx < 98304) {  // WrzT[j][k]: j<128 rW cols else zW
        int j = idx / 384, k = idx % 384;
        WrzT[idx] = f2h(j < 128 ? rW[k*128 + j] : zW[k*128 + (j-128)]);
        return;
    }
    idx -= 98304;
    if (idx < 49152) { int j = idx / 384, k = idx % 384; WtT[idx] = f2h(tW[k*128 + j]); return; }
    idx -= 49152;
    if (idx < 32768) { int j = idx / 256, k = idx % 256; WoT[idx] = f2h(oW[k*128 + j]); return; }
}

__global__ __launch_bounds__(256) void initState(const float* __restrict__ p,
                                                 float* __restrict__ sf,
                                                 ushort_t* __restrict__ sh,
                                                 ushort_t* __restrict__ ih) {
    int i = blockIdx.x * 256 + threadIdx.x;   // 524288 float4s
    float4 v = reinterpret_cast<const float4*>(p)[i];
    reinterpret_cast<float4*>(sf)[i] = v;
    using u4 = __attribute__((ext_vector_type(4))) unsigned short;
    u4 r; r[0]=f2h(v.x); r[1]=f2h(v.y); r[2]=f2h(v.z); r[3]=f2h(v.w);
    *reinterpret_cast<u4*>(sh + 4*i) = r;
    *reinterpret_cast<u4*>(ih + 4*i) = r;
}

// state_h [b][n][d] -> stateT [b][d][n] (one-time; steps 2..5 get it from t_kernel)
__global__ __launch_bounds__(256) void transT_kernel(const ushort_t* __restrict__ sh,
                                                     ushort_t* __restrict__ stateT) {
    __shared__ alignas(16) ushort_t trb[128 * 136];
    int tid = threadIdx.x, b = blockIdx.x >> 2, n0 = (blockIdx.x & 3) * 128;
#pragma unroll
    for (int rep = 0; rep < 8; ++rep) {
        int idx = rep * 256 + tid, r = idx >> 4, c8 = idx & 15;
        uint4 v = *reinterpret_cast<const uint4*>(sh + ((size_t)(b*512 + n0 + r))*128 + c8*8);
        *reinterpret_cast<uint4*>(trb + r*136 + c8*8) = v;
    }
    __syncthreads();
    int d = tid >> 1, half = tid & 1;
    ushort_t* dst = stateT + (size_t)b * 65536 + d * 512 + n0 + half * 64;
#pragma unroll
    for (int g = 0; g < 8; ++g) {
        ushort8 v;
#pragma unroll
        for (int k = 0; k < 8; ++k) v[k] = trb[(half*64 + g*8 + k)*136 + d];
        *reinterpret_cast<ushort8*>(dst + g*8) = v;
    }
}

// ---------- step kernels ----------
// G[b][n][io*512 + e*128 + h] = A_h[b,n, io*2048+e*512 : +512] @ stateT[b]   (K=512)
__global__ __launch_bounds__(256) void bigG_kernel(const ushort_t* __restrict__ A_h,
                                                   const ushort_t* __restrict__ stateT,
                                                   ushort_t* __restrict__ G) {
    __shared__ alignas(16) ushort_t lA[128*64];
    __shared__ alignas(16) ushort_t lB[128*64];
    int tid = threadIdx.x, w = tid >> 6, l15 = tid & 15, lg = (tid & 63) >> 4;
    int wm = w >> 1, wn = w & 1;
    // XCD swizzle: 32 blocks sharing stateT[b] -> same XCD (grid 1024, rr-mod-8 dispatch)
    int bx = blockIdx.x;
    int bid = (bx & 7) * 128 + (bx >> 3);
    int nt = bid & 3, e = (bid >> 2) & 3, io = (bid >> 4) & 1, b = bid >> 5;

    const ushort_t* Asrc = A_h + ((size_t)(b*512 + nt*128))*4096 + io*2048 + e*512;
    const ushort_t* Bsrc = stateT + (size_t)b * 65536;
    ushort_t* Out = G + ((size_t)(b*512 + nt*128))*1024 + io*512 + e*128;

    f32x4 acc[4][4] = {};
    for (int k0 = 0; k0 < 512; k0 += 64) {
        stage64<128>(Asrc + k0, 4096, lA, tid);
        stage64<128>(Bsrc + k0, 512, lB, tid);
        __syncthreads();
        mma64<128, 128>(lA, lB, acc, wm, wn, l15, lg);
        __syncthreads();
    }
#pragma unroll
    for (int j = 0; j < 4; ++j) {
        int col = wn*64 + j*16 + l15;
#pragma unroll
        for (int i = 0; i < 4; ++i)
#pragma unroll
            for (int q = 0; q < 4; ++q) {
                int row = wm*64 + i*16 + lg*4 + q;
                Out[(size_t)row * 1024 + col] = f2h(acc[i][j][q]);
            }
    }
}

// a_io[n][d] = G_io[n][:512] @ WstT_io + sum_e Ars[n][io*4+e] * b_io[e][d]
__global__ __launch_bounds__(256) void applyW_kernel(const ushort_t* __restrict__ G,
                                                     const ushort_t* __restrict__ WstT,
                                                     const float* __restrict__ Ars,
                                                     const float* __restrict__ in_b,
                                                     const float* __restrict__ out_b,
                                                     ushort_t* __restrict__ a_in_h,
                                                     ushort_t* __restrict__ a_out_h) {
    __shared__ alignas(16) ushort_t lA[128*64];
    __shared__ alignas(16) ushort_t lB[128*64];
    int tid = threadIdx.x, w = tid >> 6, l15 = tid & 15, lg = (tid & 63) >> 4;
    int wm = w >> 1, wn = w & 1;
    int mt = blockIdx.x >> 1, io = blockIdx.x & 1;

    const ushort_t* Asrc = G + (size_t)(mt*128)*1024 + io*512;
    const ushort_t* Bsrc = WstT + io * 65536;
    const float* bio = io ? out_b : in_b;
    ushort_t* Out = (io ? a_out_h : a_in_h);

    f32x4 acc[4][4] = {};
    for (int k0 = 0; k0 < 512; k0 += 64) {
        stage64<128>(Asrc + k0, 1024, lA, tid);
        stage64<128>(Bsrc + k0, 512, lB, tid);
        __syncthreads();
        mma64<128, 128>(lA, lB, acc, wm, wn, l15, lg);
        __syncthreads();
    }
#pragma unroll
    for (int j = 0; j < 4; ++j) {
        int col = wn*64 + j*16 + l15;
        float b0 = bio[col], b1 = bio[128+col], b2 = bio[256+col], b3 = bio[384+col];
#pragma unroll
        for (int i = 0; i < 4; ++i)
#pragma unroll
            for (int q = 0; q < 4; ++q) {
                int row = mt*128 + wm*64 + i*16 + lg*4 + q;
                float4 rs = *reinterpret_cast<const float4*>(Ars + (size_t)row*8 + io*4);
                float v = acc[i][j][q] + rs.x*b0 + rs.y*b1 + rs.z*b2 + rs.w*b3;
                Out[(size_t)row * 128 + col] = f2h(v);
            }
    }
}

// rz: preact = [a_in|a_out|state] @ [rW|zW] (K=384); cb=0 -> rsh=f16(sig*state), cb=1 -> z_f32
__global__ __launch_bounds__(256) void rz_kernel(const ushort_t* __restrict__ a_in_h,
                                                 const ushort_t* __restrict__ a_out_h,
                                                 const ushort_t* __restrict__ state_h,
                                                 const ushort_t* __restrict__ WrzT,
                                                 const float* __restrict__ rb,
                                                 const float* __restrict__ zb,
                                                 const float* __restrict__ state_f32,
                                                 ushort_t* __restrict__ rsh,
                                                 float* __restrict__ z_f32) {
    __shared__ alignas(16) ushort_t lA[128*64];
    __shared__ alignas(16) ushort_t lB[128*64];
    int tid = threadIdx.x, w = tid >> 6, l15 = tid & 15, lg = (tid & 63) >> 4;
    int wm = w >> 1, wn = w & 1;
    int mt = blockIdx.x >> 1, cb = blockIdx.x & 1;

    const ushort_t* srcs[3] = { a_in_h + (size_t)mt*128*128,
                                a_out_h + (size_t)mt*128*128,
                                state_h + (size_t)mt*128*128 };
    const ushort_t* Bsrc = WrzT + (size_t)cb * 128 * 384;

    f32x4 acc[4][4] = {};
    for (int k0 = 0; k0 < 384; k0 += 64) {
        stage64<128>(srcs[k0 >> 7] + (k0 & 127), 128, lA, tid);
        stage64<128>(Bsrc + k0, 384, lB, tid);
        __syncthreads();
        mma64<128, 128>(lA, lB, acc, wm, wn, l15, lg);
        __syncthreads();
    }
    const float* bias = cb ? zb : rb;
#pragma unroll
    for (int j = 0; j < 4; ++j) {
        int col = wn*64 + j*16 + l15;
        float bv = bias[col];
#pragma unroll
        for (int i = 0; i < 4; ++i)
#pragma unroll
            for (int q = 0; q < 4; ++q) {
                int row = mt*128 + wm*64 + i*16 + lg*4 + q;
                size_t idx = (size_t)row * 128 + col;
                float g = sigmoidf_(acc[i][j][q] + bv);
                if (cb == 0) rsh[idx] = f2h(g * state_f32[idx]);
                else         z_f32[idx] = g;
            }
    }
}

// t: h = tanh([a_in|a_out|rsh] @ tW + tb); ns=(1-z)s+zh; writes state_f32, state_h, stateT
__global__ __launch_bounds__(256) void t_kernel(const ushort_t* __restrict__ a_in_h,
                                                const ushort_t* __restrict__ a_out_h,
                                                const ushort_t* __restrict__ rsh,
                                                const ushort_t* __restrict__ WtT,
                                                const float* __restrict__ tb,
                                                const float* __restrict__ z_f32,
                                                float* __restrict__ state_f32,
                                                ushort_t* __restrict__ state_h,
                                                ushort_t* __restrict__ stateT) {
    __shared__ alignas(16) ushort_t sbuf[128 * 136];   // mma: lA=[0,8192) lB=[8192,16384); then transpose buf
    ushort_t* lA = sbuf;
    ushort_t* lB = sbuf + 8192;
    int tid = threadIdx.x, w = tid >> 6, l15 = tid & 15, lg = (tid & 63) >> 4;
    int wm = w >> 1, wn = w & 1;
    int mt = blockIdx.x;

    const ushort_t* srcs[3] = { a_in_h + (size_t)mt*128*128,
                                a_out_h + (size_t)mt*128*128,
                                rsh + (size_t)mt*128*128 };
    f32x4 acc[4][4] = {};
    for (int k0 = 0; k0 < 384; k0 += 64) {
        stage64<128>(srcs[k0 >> 7] + (k0 & 127), 128, lA, tid);
        stage64<128>(WtT + k0, 384, lB, tid);
        __syncthreads();
        mma64<128, 128>(lA, lB, acc, wm, wn, l15, lg);
        __syncthreads();
    }
#pragma unroll
    for (int j = 0; j < 4; ++j) {
        int col = wn*64 + j*16 + l15;
        float bv = tb[col];
#pragma unroll
        for (int i = 0; i < 4; ++i)
#pragma unroll
            for (int q = 0; q < 4; ++q) {
                int lrow = wm*64 + i*16 + lg*4 + q;
                int row = mt*128 + lrow;
                size_t idx = (size_t)row * 128 + col;
                float h = tanhf(acc[i][j][q] + bv);
                float z = z_f32[idx];
                float ns = (1.0f - z) * state_f32[idx] + z * h;
                state_f32[idx] = ns;
                ushort_t nh = f2h(ns);
                state_h[idx] = nh;
                sbuf[lrow * 136 + col] = nh;
            }
    }
    __syncthreads();
    int b = mt >> 2, n0 = (mt & 3) * 128;
    int d = tid >> 1, half = tid & 1;
    ushort_t* dst = stateT + (size_t)b * 65536 + d * 512 + n0 + half * 64;
#pragma unroll
    for (int g = 0; g < 8; ++g) {
        ushort8 v;
#pragma unroll
        for (int k = 0; k < 8; ++k) v[k] = sbuf[(half*64 + g*8 + k)*136 + d];
        *reinterpret_cast<ushort8*>(dst + g*8) = v;
    }
}

// final: out = tanh([state|init] @ oW + ob)  (K=256)
__global__ __launch_bounds__(256) void final_kernel(const ushort_t* __restrict__ state_h,
                                                    const ushort_t* __restrict__ init_h,
                                                    const ushort_t* __restrict__ WoT,
                                                    const float* __restrict__ ob,
                                                    float* __restrict__ out) {
    __shared__ alignas(16) ushort_t lA[128*64];
    __shared__ alignas(16) ushort_t lB[128*64];
    int tid = threadIdx.x, w = tid >> 6, l15 = tid & 15, lg = (tid & 63) >> 4;
    int wm = w >> 1, wn = w & 1;
    int mt = blockIdx.x;

    const ushort_t* srcs[2] = { state_h + (size_t)mt*128*128,
                                init_h + (size_t)mt*128*128 };
    f32x4 acc[4][4] = {};
    for (int k0 = 0; k0 < 256; k0 += 64) {
        stage64<128>(srcs[k0 >> 7] + (k0 & 127), 128, lA, tid);
        stage64<128>(WoT + k0, 256, lB, tid);
        __syncthreads();
        mma64<128, 128>(lA, lB, acc, wm, wn, l15, lg);
        __syncthreads();
    }
#pragma unroll
    for (int j = 0; j < 4; ++j) {
        int col = wn*64 + j*16 + l15;
        float bv = ob[col];
#pragma unroll
        for (int i = 0; i < 4; ++i)
#pragma unroll
            for (int q = 0; q < 4; ++q) {
                int row = mt*128 + wm*64 + i*16 + lg*4 + q;
                out[(size_t)row * 128 + col] = tanhf(acc[i][j][q] + bv);
            }
    }
}

// ---------- launch ----------
extern "C" void kernel_launch(void* const* d_in, const int* in_sizes, int n_in,
                              void* d_out, int out_size, void* d_ws, size_t ws_size,
                              hipStream_t stream) {
    const float* prop  = (const float*)d_in[0];
    const float* A     = (const float*)d_in[1];
    const float* in_W  = (const float*)d_in[3];
    const float* in_b  = (const float*)d_in[4];
    const float* out_W = (const float*)d_in[5];
    const float* out_b = (const float*)d_in[6];
    const float* rW    = (const float*)d_in[7];
    const float* rb    = (const float*)d_in[8];
    const float* zW    = (const float*)d_in[9];
    const float* zb    = (const float*)d_in[10];
    const float* tW    = (const float*)d_in[11];
    const float* tb    = (const float*)d_in[12];
    const float* oW    = (const float*)d_in[13];
    const float* ob    = (const float*)d_in[14];
    float* outp = (float*)d_out;

    size_t off = 0;
    auto carve = [&](size_t bytes) {
        void* p = (char*)d_ws + off;
        off += (bytes + 255) & ~(size_t)255;
        return p;
    };
    ushort_t* A_h      = (ushort_t*)carve((size_t)M_TOT*4096*2);   // 134 MB
    ushort_t* G        = (ushort_t*)carve((size_t)M_TOT*1024*2);   // 33.6 MB
    ushort_t* stateT   = (ushort_t*)carve((size_t)B_*D_*N_*2);     // 4.2 MB
    ushort_t* a_in_h   = (ushort_t*)carve((size_t)M_TOT*D_*2);
    ushort_t* a_out_h  = (ushort_t*)carve((size_t)M_TOT*D_*2);
    ushort_t* rsh      = (ushort_t*)carve((size_t)M_TOT*D_*2);
    ushort_t* state_h  = (ushort_t*)carve((size_t)M_TOT*D_*2);
    ushort_t* init_h   = (ushort_t*)carve((size_t)M_TOT*D_*2);
    float*    state_f32= (float*)carve((size_t)M_TOT*D_*4);
    float*    z_f32    = (float*)carve((size_t)M_TOT*D_*4);
    float*    Ars      = (float*)carve((size_t)M_TOT*8*4);
    ushort_t* WstT     = (ushort_t*)carve((size_t)2*128*512*2);
    ushort_t* WrzT     = (ushort_t*)carve((size_t)256*384*2);
    ushort_t* WtT      = (ushort_t*)carve((size_t)128*384*2);
    ushort_t* WoT      = (ushort_t*)carve((size_t)128*256*2);
    (void)ws_size; (void)n_in; (void)in_sizes; (void)out_size;

    convertA_rs<<<16384, 256, 0, stream>>>(A, A_h, Ars);
    prep_weights<<<1216, 256, 0, stream>>>(in_W, out_W, rW, zW, tW, oW, WstT, WrzT, WtT, WoT);
    initState<<<2048, 256, 0, stream>>>(prop, state_f32, state_h, init_h);
    transT_kernel<<<128, 256, 0, stream>>>(state_h, stateT);

    for (int s = 0; s < STEPS_; ++s) {
        bigG_kernel<<<1024, 256, 0, stream>>>(A_h, stateT, G);
        applyW_kernel<<<256, 256, 0, stream>>>(G, WstT, Ars, in_b, out_b, a_in_h, a_out_h);
        rz_kernel<<<256, 256, 0, stream>>>(a_in_h, a_out_h, state_h, WrzT, rb, zb,
                                           state_f32, rsh, z_f32);
        t_kernel<<<128, 256, 0, stream>>>(a_in_h, a_out_h, rsh, WtT, tb, z_f32,
                                          state_f32, state_h, stateT);
    }
    final_kernel<<<128, 256, 0, stream>>>(state_h, init_h, WoT, ob, outp);
}

// Round 5
// 832.237 us; speedup vs baseline: 1.2530x; 1.2003x over previous
//
#include <hip/hip_runtime.h>

#define DEV __device__ __forceinline__

using half8   = __attribute__((ext_vector_type(8))) _Float16;
using ushort8 = __attribute__((ext_vector_type(8))) unsigned short;
using f32x4   = __attribute__((ext_vector_type(4))) float;

typedef unsigned short ushort_t;

constexpr int B_ = 32, N_ = 512, E_ = 4, D_ = 128;
constexpr int NE = N_ * E_;        // 2048
constexpr int M_TOT = B_ * N_;     // 16384
constexpr int STEPS_ = 5;

// ---------- helpers ----------
DEV ushort_t f2h(float x) { union { _Float16 h; ushort_t u; } v; v.h = (_Float16)x; return v.u; }
DEV float sigmoidf_(float x) { return 1.0f / (1.0f + __expf(-x)); }

// async global->LDS staging of ROWS x 64 f16 tile (BK=64). LDS linear [ROWS][64].
template<int ROWS>
DEV void stage64(const ushort_t* __restrict__ g, int ld, ushort_t* lds, int tid) {
    constexpr int TOT = ROWS * 8;          // 16B chunks (8 per row)
    static_assert(TOT % 256 == 0, "");
    int w = tid >> 6, lane = tid & 63;
#pragma unroll
    for (int c0 = 0; c0 < TOT; c0 += 256) {
        int c  = c0 + (w << 6) + lane;
        int r  = c >> 3;
        int cc = c & 7;
        __builtin_amdgcn_global_load_lds(
            (__attribute__((address_space(1))) void*)(g + r * ld + cc * 8),
            (__attribute__((address_space(3))) void*)(lds + (c0 + (w << 6)) * 8),
            16, 0, 0);
    }
}

// swizzled f16 store into an LDS tile with logical layout [rows][LDA=128]
DEV void st_swz(ushort_t* base, int row, int col, ushort_t v) {
    int off = ((row * 128 + col) * 2) ^ ((row & 7) << 4);
    *reinterpret_cast<ushort_t*>(reinterpret_cast<char*>(base) + off) = v;
}

// one BK=64 K-step. A: LDS tile [BM][LDA] (optionally XOR-swizzled), window at k0.
// B: staged LDS [BN][64] linear (row = output col). 4 waves as 2x2.
template<int BM, int BN, int LDA, bool SWZ>
DEV void mmaT(const ushort_t* lA, int k0, const ushort_t* lB,
              f32x4 (&acc)[BM/32][BN/32], int wm, int wn, int l15, int lg) {
    constexpr int MF = BM/32, NF = BN/32;
#pragma unroll
    for (int kk = 0; kk < 2; ++kk) {
        half8 a[MF], b[NF];
#pragma unroll
        for (int i = 0; i < MF; ++i) {
            int row = wm*(BM/2) + i*16 + l15;
            int off = (row*LDA + k0 + kk*32 + lg*8) * 2;
            if (SWZ) off ^= (row & 7) << 4;
            a[i] = *reinterpret_cast<const half8*>(reinterpret_cast<const char*>(lA) + off);
        }
#pragma unroll
        for (int j = 0; j < NF; ++j)
            b[j] = *reinterpret_cast<const half8*>(lB + (wn*(BN/2)+j*16+l15)*64 + kk*32 + lg*8);
#pragma unroll
        for (int i = 0; i < MF; ++i)
#pragma unroll
            for (int j = 0; j < NF; ++j)
                acc[i][j] = __builtin_amdgcn_mfma_f32_16x16x32_f16(a[i], b[j], acc[i][j], 0, 0, 0);
    }
}

DEV void zacc(f32x4 (&acc)[2][4]) {
#pragma unroll
    for (int i = 0; i < 2; ++i)
#pragma unroll
        for (int j = 0; j < 4; ++j) acc[i][j] = (f32x4){0.f,0.f,0.f,0.f};
}

// ---------- prep ----------
__global__ __launch_bounds__(256) void convertA_rs(const float* __restrict__ A,
                                                   ushort_t* __restrict__ A_h,
                                                   float* __restrict__ Ars) {
    int row = blockIdx.x, t = threadIdx.x;
    const float* src = A + (size_t)row * 4096 + t * 16;
    ushort_t* dst = A_h + (size_t)row * 4096 + t * 16;
    float s = 0.f;
#pragma unroll
    for (int c = 0; c < 2; ++c) {
        float4 v0 = reinterpret_cast<const float4*>(src)[2*c];
        float4 v1 = reinterpret_cast<const float4*>(src)[2*c+1];
        s += v0.x+v0.y+v0.z+v0.w + v1.x+v1.y+v1.z+v1.w;
        ushort8 r;
        r[0]=f2h(v0.x); r[1]=f2h(v0.y); r[2]=f2h(v0.z); r[3]=f2h(v0.w);
        r[4]=f2h(v1.x); r[5]=f2h(v1.y); r[6]=f2h(v1.z); r[7]=f2h(v1.w);
        *reinterpret_cast<ushort8*>(dst + 8*c) = r;
    }
#pragma unroll
    for (int m = 16; m; m >>= 1) s += __shfl_xor(s, m);
    if ((t & 31) == 0) Ars[(size_t)row * 8 + (t >> 5)] = s;
}

__global__ __launch_bounds__(256) void prep_weights(
    const float* __restrict__ in_W, const float* __restrict__ out_W,
    const float* __restrict__ rW, const float* __restrict__ zW,
    const float* __restrict__ tW, const float* __restrict__ oW,
    ushort_t* WstT, ushort_t* WrzT, ushort_t* WtT, ushort_t* WoT) {
    int idx = blockIdx.x * 256 + threadIdx.x;
    if (idx < 131072) {  // WstT[io][out][e*128+x] = W_io[e][x][out]
        int io = idx >> 16, r = idx & 65535, d = r >> 9, eh = r & 511, e = eh >> 7, h = eh & 127;
        const float* W = io ? out_W : in_W;
        WstT[idx] = f2h(W[e*16384 + h*128 + d]);
        return;
    }
    idx -= 131072;
    if (idx < 98304) {  // WrzT[j][k]: j<128 rW cols else zW
        int j = idx / 384, k = idx % 384;
        WrzT[idx] = f2h(j < 128 ? rW[k*128 + j] : zW[k*128 + (j-128)]);
        return;
    }
    idx -= 98304;
    if (idx < 49152) { int j = idx / 384, k = idx % 384; WtT[idx] = f2h(tW[k*128 + j]); return; }
    idx -= 49152;
    if (idx < 32768) { int j = idx / 256, k = idx % 256; WoT[idx] = f2h(oW[k*128 + j]); return; }
}

// init: state_f32 / state_h / init_h + stateT transpose, fused. 128 blocks x 128 rows.
__global__ __launch_bounds__(256) void initPlus(const float* __restrict__ p,
                                                float* __restrict__ sf,
                                                ushort_t* __restrict__ sh,
                                                ushort_t* __restrict__ ih,
                                                ushort_t* __restrict__ stateT) {
    __shared__ ushort_t trb[128 * 132];
    int tid = threadIdx.x, mt = blockIdx.x;
    size_t base = (size_t)mt * 128 * 128;
#pragma unroll
    for (int rep = 0; rep < 16; ++rep) {
        int idx = rep * 256 + tid, row = idx >> 5, c4 = idx & 31;
        size_t o = base + (size_t)row * 128 + c4 * 4;
        float4 v = *reinterpret_cast<const float4*>(p + o);
        *reinterpret_cast<float4*>(sf + o) = v;
        using u4 = __attribute__((ext_vector_type(4))) unsigned short;
        u4 r; r[0]=f2h(v.x); r[1]=f2h(v.y); r[2]=f2h(v.z); r[3]=f2h(v.w);
        *reinterpret_cast<u4*>(sh + o) = r;
        *reinterpret_cast<u4*>(ih + o) = r;
        trb[row*132 + c4*4 + 0] = r[0]; trb[row*132 + c4*4 + 1] = r[1];
        trb[row*132 + c4*4 + 2] = r[2]; trb[row*132 + c4*4 + 3] = r[3];
    }
    __syncthreads();
    int b = mt >> 2, n0 = (mt & 3) * 128, d = tid >> 1, half = tid & 1;
    ushort_t* dst = stateT + (size_t)b * 65536 + (size_t)d * 512 + n0 + half * 64;
#pragma unroll
    for (int g2 = 0; g2 < 8; ++g2) {
        ushort8 v;
#pragma unroll
        for (int k = 0; k < 8; ++k) v[k] = trb[(half*64 + g2*8 + k)*132 + d];
        *reinterpret_cast<ushort8*>(dst + g2*8) = v;
    }
}

// ---------- step kernels ----------
// G[b][n][io*512 + e*128 + x] = A_h[b,n, io*2048+e*512+n'] @ state[n'][x]   (K=512)
__global__ __launch_bounds__(256) void bigG_kernel(const ushort_t* __restrict__ A_h,
                                                   const ushort_t* __restrict__ stateT,
                                                   ushort_t* __restrict__ G) {
    __shared__ char smem[128*136*2] __attribute__((aligned(16)));   // 34816 B
    ushort_t* sA  = (ushort_t*)smem;
    ushort_t* sB  = (ushort_t*)(smem + 16384);
    ushort_t* buf = (ushort_t*)smem;   // epilogue bounce [128][136]
    int tid = threadIdx.x, w = tid >> 6, l15 = tid & 15, lg = (tid & 63) >> 4;
    int wm = w >> 1, wn = w & 1;
    // XCD swizzle: each XCD gets 128 consecutive bids = 4 b values (stateT 512KB in its L2)
    int bx = blockIdx.x;
    int bid = (bx & 7) * 128 + (bx >> 3);
    int nt = bid & 3, e = (bid >> 2) & 3, io = (bid >> 4) & 1, b = bid >> 5;

    const ushort_t* Asrc = A_h + ((size_t)(b*512 + nt*128))*4096 + io*2048 + e*512;
    const ushort_t* Bsrc = stateT + (size_t)b * 65536;
    ushort_t* Out = G + ((size_t)(b*512 + nt*128))*1024 + io*512 + e*128;

    f32x4 acc[4][4] = {};
    for (int k0 = 0; k0 < 512; k0 += 64) {
        stage64<128>(Asrc + k0, 4096, sA, tid);
        stage64<128>(Bsrc + k0, 512, sB, tid);
        __syncthreads();
        mmaT<128, 128, 64, false>(sA, 0, sB, acc, wm, wn, l15, lg);
        __syncthreads();
    }
    // coalesced store via LDS bounce
#pragma unroll
    for (int j = 0; j < 4; ++j) {
        int col = wn*64 + j*16 + l15;
#pragma unroll
        for (int i = 0; i < 4; ++i)
#pragma unroll
            for (int q = 0; q < 4; ++q) {
                int row = wm*64 + i*16 + lg*4 + q;
                buf[row*136 + col] = f2h(acc[i][j][q]);
            }
    }
    __syncthreads();
#pragma unroll
    for (int rep = 0; rep < 8; ++rep) {
        int idx = rep*256 + tid, row = idx >> 4, c8 = idx & 15;
        uint4 v = *reinterpret_cast<uint4*>(buf + row*136 + c8*8);
        *reinterpret_cast<uint4*>(Out + (size_t)row*1024 + c8*8) = v;
    }
}

// fused GRU: a_in/a_out (K=512 each) -> r (K=384) -> z (K=384) -> h/update (K=384)
// 256 blocks x 64 rows. a_in/a_out/rs live in LDS (XOR-swizzled); z in registers.
__global__ __launch_bounds__(256, 2) void gru_kernel(
    const ushort_t* __restrict__ G, const ushort_t* __restrict__ WstT,
    const float* __restrict__ Ars, const float* __restrict__ in_b,
    const float* __restrict__ out_b,
    const ushort_t* __restrict__ WrzT, const float* __restrict__ rb,
    const float* __restrict__ zb,
    const ushort_t* __restrict__ WtT, const float* __restrict__ tb,
    float* __restrict__ state_f32, ushort_t* __restrict__ state_h,
    ushort_t* __restrict__ stateT) {
    __shared__ char smem[73728] __attribute__((aligned(16)));
    ushort_t* sA    = (ushort_t*)smem;            //  8 KB staging [64][64]
    ushort_t* sB    = (ushort_t*)(smem + 8192);   // 16 KB staging [128][64]
    ushort_t* a_in  = (ushort_t*)(smem + 24576);  // 16 KB [64][128] swz
    ushort_t* a_out = (ushort_t*)(smem + 40960);  // 16 KB
    ushort_t* rsb   = (ushort_t*)(smem + 57344);  // 16 KB
    ushort_t* trb   = (ushort_t*)smem;            // reuse: [64][132] = 16.5 KB

    int tid = threadIdx.x, w = tid >> 6, l15 = tid & 15, lg = (tid & 63) >> 4;
    int wm = w >> 1, wn = w & 1;
    int grow0 = blockIdx.x * 64;

    f32x4 acc[2][4];
    f32x4 zr[2][4];

#define GRU_KSTEP_GLB(APTR, ALD, BPTR, BLD) do {                         \
        stage64<64>((APTR), (ALD), sA, tid);                             \
        stage64<128>((BPTR), (BLD), sB, tid);                            \
        __syncthreads();                                                 \
        mmaT<64,128,64,false>(sA, 0, sB, acc, wm, wn, l15, lg);          \
        __syncthreads(); } while (0)

#define GRU_KSTEP_LDS(ABASE, K0, BPTR, BLD) do {                         \
        stage64<128>((BPTR), (BLD), sB, tid);                            \
        __syncthreads();                                                 \
        mmaT<64,128,128,true>((ABASE), (K0), sB, acc, wm, wn, l15, lg);  \
        __syncthreads(); } while (0)

    // ---- Phase A: a_io = G_io @ WstT_io + rowsum*bias ----
    for (int io = 0; io < 2; ++io) {
        zacc(acc);
        for (int k0 = 0; k0 < 512; k0 += 64) {
            GRU_KSTEP_GLB(G + (size_t)grow0*1024 + io*512 + k0, 1024,
                          WstT + io*65536 + k0, 512);
        }
        const float* bio = io ? out_b : in_b;
        ushort_t* adst = io ? a_out : a_in;
#pragma unroll
        for (int j = 0; j < 4; ++j) {
            int col = wn*64 + j*16 + l15;
            float b0 = bio[col], b1 = bio[128+col], b2 = bio[256+col], b3 = bio[384+col];
#pragma unroll
            for (int i = 0; i < 2; ++i)
#pragma unroll
                for (int q = 0; q < 4; ++q) {
                    int row = wm*32 + i*16 + lg*4 + q;
                    float4 rsv = *reinterpret_cast<const float4*>(Ars + (size_t)(grow0+row)*8 + io*4);
                    float v = acc[i][j][q] + rsv.x*b0 + rsv.y*b1 + rsv.z*b2 + rsv.w*b3;
                    st_swz(adst, row, col, f2h(v));
                }
        }
    }

    // ---- Phase B-r: r = sigmoid([a_in|a_out|state]@rW + rb); rs = r*s ----
    zacc(acc);
    GRU_KSTEP_LDS(a_in,  0,  WrzT + 0,   384);
    GRU_KSTEP_LDS(a_in,  64, WrzT + 64,  384);
    GRU_KSTEP_LDS(a_out, 0,  WrzT + 128, 384);
    GRU_KSTEP_LDS(a_out, 64, WrzT + 192, 384);
    GRU_KSTEP_GLB(state_h + (size_t)grow0*128,      128, WrzT + 256, 384);
    GRU_KSTEP_GLB(state_h + (size_t)grow0*128 + 64, 128, WrzT + 320, 384);
#pragma unroll
    for (int j = 0; j < 4; ++j) {
        int col = wn*64 + j*16 + l15;
        float rbv = rb[col];
#pragma unroll
        for (int i = 0; i < 2; ++i)
#pragma unroll
            for (int q = 0; q < 4; ++q) {
                int row = wm*32 + i*16 + lg*4 + q;
                size_t idx = (size_t)(grow0+row)*128 + col;
                float rg = sigmoidf_(acc[i][j][q] + rbv);
                st_swz(rsb, row, col, f2h(rg * state_f32[idx]));
            }
    }

    // ---- Phase B-z: z (kept in registers; same fragment layout as h) ----
    zacc(acc);
    {
        const ushort_t* Wz = WrzT + 128*384;
        GRU_KSTEP_LDS(a_in,  0,  Wz + 0,   384);
        GRU_KSTEP_LDS(a_in,  64, Wz + 64,  384);
        GRU_KSTEP_LDS(a_out, 0,  Wz + 128, 384);
        GRU_KSTEP_LDS(a_out, 64, Wz + 192, 384);
        GRU_KSTEP_GLB(state_h + (size_t)grow0*128,      128, Wz + 256, 384);
        GRU_KSTEP_GLB(state_h + (size_t)grow0*128 + 64, 128, Wz + 320, 384);
    }
#pragma unroll
    for (int j = 0; j < 4; ++j) {
        int col = wn*64 + j*16 + l15;
        float zbv = zb[col];
#pragma unroll
        for (int i = 0; i < 2; ++i)
#pragma unroll
            for (int q = 0; q < 4; ++q)
                zr[i][j][q] = sigmoidf_(acc[i][j][q] + zbv);
    }

    // ---- Phase C: h = tanh([a_in|a_out|rs]@tW + tb); ns = (1-z)s + zh ----
    zacc(acc);
    GRU_KSTEP_LDS(a_in,  0,  WtT + 0,   384);
    GRU_KSTEP_LDS(a_in,  64, WtT + 64,  384);
    GRU_KSTEP_LDS(a_out, 0,  WtT + 128, 384);
    GRU_KSTEP_LDS(a_out, 64, WtT + 192, 384);
    GRU_KSTEP_LDS(rsb,   0,  WtT + 256, 384);
    GRU_KSTEP_LDS(rsb,   64, WtT + 320, 384);
#pragma unroll
    for (int j = 0; j < 4; ++j) {
        int col = wn*64 + j*16 + l15;
        float tbv = tb[col];
#pragma unroll
        for (int i = 0; i < 2; ++i)
#pragma unroll
            for (int q = 0; q < 4; ++q) {
                int row = wm*32 + i*16 + lg*4 + q;
                size_t idx = (size_t)(grow0+row)*128 + col;
                float h = tanhf(acc[i][j][q] + tbv);
                float z = zr[i][j][q];
                float ns = (1.0f - z) * state_f32[idx] + z * h;
                state_f32[idx] = ns;
                trb[row*132 + col] = f2h(ns);
            }
    }
    __syncthreads();
    // coalesced state_h from trb
#pragma unroll
    for (int rep = 0; rep < 4; ++rep) {
        int idx = rep*256 + tid, row = idx >> 4, c8 = idx & 15;
        ushort8 v;
#pragma unroll
        for (int k = 0; k < 8; ++k) v[k] = trb[row*132 + c8*8 + k];
        *reinterpret_cast<ushort8*>(state_h + (size_t)(grow0+row)*128 + c8*8) = v;
    }
    // stateT transpose-out
    {
        int b = grow0 >> 9, n0 = grow0 & 511, d = tid >> 1, half = tid & 1;
        ushort_t* dst = stateT + (size_t)b*65536 + (size_t)d*512 + n0 + half*32;
#pragma unroll
        for (int g2 = 0; g2 < 4; ++g2) {
            ushort8 v;
#pragma unroll
            for (int k = 0; k < 8; ++k) v[k] = trb[(half*32 + g2*8 + k)*132 + d];
            *reinterpret_cast<ushort8*>(dst + g2*8) = v;
        }
    }
#undef GRU_KSTEP_GLB
#undef GRU_KSTEP_LDS
}

// final: out = tanh([state|init] @ oW + ob)  (K=256)
__global__ __launch_bounds__(256) void final_kernel(const ushort_t* __restrict__ state_h,
                                                    const ushort_t* __restrict__ init_h,
                                                    const ushort_t* __restrict__ WoT,
                                                    const float* __restrict__ ob,
                                                    float* __restrict__ out) {
    __shared__ alignas(16) ushort_t lA[128*64];
    __shared__ alignas(16) ushort_t lB[128*64];
    int tid = threadIdx.x, w = tid >> 6, l15 = tid & 15, lg = (tid & 63) >> 4;
    int wm = w >> 1, wn = w & 1;
    int mt = blockIdx.x;

    const ushort_t* srcs[2] = { state_h + (size_t)mt*128*128,
                                init_h + (size_t)mt*128*128 };
    f32x4 acc[4][4] = {};
    for (int k0 = 0; k0 < 256; k0 += 64) {
        stage64<128>(srcs[k0 >> 7] + (k0 & 127), 128, lA, tid);
        stage64<128>(WoT + k0, 256, lB, tid);
        __syncthreads();
        mmaT<128, 128, 64, false>(lA, 0, lB, acc, wm, wn, l15, lg);
        __syncthreads();
    }
#pragma unroll
    for (int j = 0; j < 4; ++j) {
        int col = wn*64 + j*16 + l15;
        float bv = ob[col];
#pragma unroll
        for (int i = 0; i < 4; ++i)
#pragma unroll
            for (int q = 0; q < 4; ++q) {
                int row = mt*128 + wm*64 + i*16 + lg*4 + q;
                out[(size_t)row * 128 + col] = tanhf(acc[i][j][q] + bv);
            }
    }
}

// ---------- launch ----------
extern "C" void kernel_launch(void* const* d_in, const int* in_sizes, int n_in,
                              void* d_out, int out_size, void* d_ws, size_t ws_size,
                              hipStream_t stream) {
    const float* prop  = (const float*)d_in[0];
    const float* A     = (const float*)d_in[1];
    const float* in_W  = (const float*)d_in[3];
    const float* in_b  = (const float*)d_in[4];
    const float* out_W = (const float*)d_in[5];
    const float* out_b = (const float*)d_in[6];
    const float* rW    = (const float*)d_in[7];
    const float* rb    = (const float*)d_in[8];
    const float* zW    = (const float*)d_in[9];
    const float* zb    = (const float*)d_in[10];
    const float* tW    = (const float*)d_in[11];
    const float* tb    = (const float*)d_in[12];
    const float* oW    = (const float*)d_in[13];
    const float* ob    = (const float*)d_in[14];
    float* outp = (float*)d_out;

    size_t off = 0;
    auto carve = [&](size_t bytes) {
        void* p = (char*)d_ws + off;
        off += (bytes + 255) & ~(size_t)255;
        return p;
    };
    ushort_t* A_h      = (ushort_t*)carve((size_t)M_TOT*4096*2);   // 134 MB
    ushort_t* G        = (ushort_t*)carve((size_t)M_TOT*1024*2);   // 33.6 MB
    ushort_t* stateT   = (ushort_t*)carve((size_t)B_*D_*N_*2);     // 4.2 MB
    ushort_t* state_h  = (ushort_t*)carve((size_t)M_TOT*D_*2);
    ushort_t* init_h   = (ushort_t*)carve((size_t)M_TOT*D_*2);
    float*    state_f32= (float*)carve((size_t)M_TOT*D_*4);
    float*    Ars      = (float*)carve((size_t)M_TOT*8*4);
    ushort_t* WstT     = (ushort_t*)carve((size_t)2*128*512*2);
    ushort_t* WrzT     = (ushort_t*)carve((size_t)256*384*2);
    ushort_t* WtT      = (ushort_t*)carve((size_t)128*384*2);
    ushort_t* WoT      = (ushort_t*)carve((size_t)128*256*2);
    (void)ws_size; (void)n_in; (void)in_sizes; (void)out_size;

    convertA_rs<<<16384, 256, 0, stream>>>(A, A_h, Ars);
    prep_weights<<<1216, 256, 0, stream>>>(in_W, out_W, rW, zW, tW, oW, WstT, WrzT, WtT, WoT);
    initPlus<<<128, 256, 0, stream>>>(prop, state_f32, state_h, init_h, stateT);

    for (int s = 0; s < STEPS_; ++s) {
        bigG_kernel<<<1024, 256, 0, stream>>>(A_h, stateT, G);
        gru_kernel<<<256, 256, 0, stream>>>(G, WstT, Ars, in_b, out_b,
                                            WrzT, rb, zb, WtT, tb,
                                            state_f32, state_h, stateT);
    }
    final_kernel<<<128, 256, 0, stream>>>(state_h, init_h, WoT, ob, outp);
}

// Round 9
// 830.531 us; speedup vs baseline: 1.2556x; 1.0021x over previous
//
#include <hip/hip_runtime.h>

#define DEV __device__ __forceinline__

using half8   = __attribute__((ext_vector_type(8))) _Float16;
using ushort8 = __attribute__((ext_vector_type(8))) unsigned short;
using f32x4   = __attribute__((ext_vector_type(4))) float;

typedef unsigned short ushort_t;

constexpr int B_ = 32, N_ = 512, E_ = 4, D_ = 128;
constexpr int NE = N_ * E_;        // 2048
constexpr int M_TOT = B_ * N_;     // 16384
constexpr int STEPS_ = 5;

// ---------- helpers ----------
DEV ushort_t f2h(float x) { union { _Float16 h; ushort_t u; } v; v.h = (_Float16)x; return v.u; }
DEV float sigmoidf_(float x) { return 1.0f / (1.0f + __expf(-x)); }

// async global->LDS staging of ROWS x 64 f16 tile. LDS linear [ROWS][64].
template<int ROWS>
DEV void stage64(const ushort_t* __restrict__ g, int ld, ushort_t* lds, int tid) {
    constexpr int TOT = ROWS * 8;          // 16B chunks (8 per row)
    static_assert(TOT % 256 == 0, "");
    int w = tid >> 6, lane = tid & 63;
#pragma unroll
    for (int c0 = 0; c0 < TOT; c0 += 256) {
        int c  = c0 + (w << 6) + lane;
        int r  = c >> 3;
        int cc = c & 7;
        __builtin_amdgcn_global_load_lds(
            (__attribute__((address_space(1))) void*)(g + r * ld + cc * 8),
            (__attribute__((address_space(3))) void*)(lds + (c0 + (w << 6)) * 8),
            16, 0, 0);
    }
}

// swizzled f16 store into an LDS tile with logical layout [rows][128]
DEV void st_swz(ushort_t* base, int row, int col, ushort_t v) {
    int off = ((row * 128 + col) * 2) ^ ((row & 7) << 4);
    *reinterpret_cast<ushort_t*>(reinterpret_cast<char*>(base) + off) = v;
}

// one BK=64 K-step. A: LDS tile [BM][LDA] (optionally XOR-swizzled), window at k0.
// B: staged LDS [BN][64] linear (row = output col). 4 waves as 2x2.
template<int BM, int BN, int LDA, bool SWZ>
DEV void mmaT(const ushort_t* lA, int k0, const ushort_t* lB,
              f32x4 (&acc)[BM/32][BN/32], int wm, int wn, int l15, int lg) {
    constexpr int MF = BM/32, NF = BN/32;
#pragma unroll
    for (int kk = 0; kk < 2; ++kk) {
        half8 a[MF], b[NF];
#pragma unroll
        for (int i = 0; i < MF; ++i) {
            int row = wm*(BM/2) + i*16 + l15;
            int off = (row*LDA + k0 + kk*32 + lg*8) * 2;
            if (SWZ) off ^= (row & 7) << 4;
            a[i] = *reinterpret_cast<const half8*>(reinterpret_cast<const char*>(lA) + off);
        }
#pragma unroll
        for (int j = 0; j < NF; ++j)
            b[j] = *reinterpret_cast<const half8*>(lB + (wn*(BN/2)+j*16+l15)*64 + kk*32 + lg*8);
#pragma unroll
        for (int i = 0; i < MF; ++i)
#pragma unroll
            for (int j = 0; j < NF; ++j)
                acc[i][j] = __builtin_amdgcn_mfma_f32_16x16x32_f16(a[i], b[j], acc[i][j], 0, 0, 0);
    }
}

template<int MF, int NF>
DEV void zaccT(f32x4 (&a)[MF][NF]) {
#pragma unroll
    for (int i = 0; i < MF; ++i)
#pragma unroll
        for (int j = 0; j < NF; ++j) a[i][j] = (f32x4){0.f,0.f,0.f,0.f};
}

// ---------- prep ----------
__global__ __launch_bounds__(256) void convertA_rs(const float* __restrict__ A,
                                                   ushort_t* __restrict__ A_h,
                                                   float* __restrict__ Ars) {
    int row = blockIdx.x, t = threadIdx.x;
    const float* src = A + (size_t)row * 4096 + t * 16;
    ushort_t* dst = A_h + (size_t)row * 4096 + t * 16;
    float s = 0.f;
#pragma unroll
    for (int c = 0; c < 2; ++c) {
        float4 v0 = reinterpret_cast<const float4*>(src)[2*c];
        float4 v1 = reinterpret_cast<const float4*>(src)[2*c+1];
        s += v0.x+v0.y+v0.z+v0.w + v1.x+v1.y+v1.z+v1.w;
        ushort8 r;
        r[0]=f2h(v0.x); r[1]=f2h(v0.y); r[2]=f2h(v0.z); r[3]=f2h(v0.w);
        r[4]=f2h(v1.x); r[5]=f2h(v1.y); r[6]=f2h(v1.z); r[7]=f2h(v1.w);
        *reinterpret_cast<ushort8*>(dst + 8*c) = r;
    }
#pragma unroll
    for (int m = 16; m; m >>= 1) s += __shfl_xor(s, m);
    if ((t & 31) == 0) Ars[(size_t)row * 8 + (t >> 5)] = s;
}

__global__ __launch_bounds__(256) void prep_weights(
    const float* __restrict__ in_W, const float* __restrict__ out_W,
    const float* __restrict__ rW, const float* __restrict__ zW,
    const float* __restrict__ tW, const float* __restrict__ oW,
    ushort_t* WstT, ushort_t* WrzT, ushort_t* WtT, ushort_t* WoT) {
    int idx = blockIdx.x * 256 + threadIdx.x;
    if (idx < 131072) {  // WstT[io][out][e*128+in] = W_io[e][in][out]
        int io = idx >> 16, r = idx & 65535, d = r >> 9, eh = r & 511, e = eh >> 7, h = eh & 127;
        const float* W = io ? out_W : in_W;
        WstT[idx] = f2h(W[e*16384 + h*128 + d]);
        return;
    }
    idx -= 131072;
    if (idx < 98304) {  // WrzT[j][k]: j<128 rW cols else zW
        int j = idx / 384, k = idx % 384;
        WrzT[idx] = f2h(j < 128 ? rW[k*128 + j] : zW[k*128 + (j-128)]);
        return;
    }
    idx -= 98304;
    if (idx < 49152) { int j = idx / 384, k = idx % 384; WtT[idx] = f2h(tW[k*128 + j]); return; }
    idx -= 49152;
    if (idx < 32768) { int j = idx / 256, k = idx % 256; WoT[idx] = f2h(oW[k*128 + j]); return; }
}

// init: state_f32 / state_h / init_h + stateT transpose, fused. 128 blocks x 128 rows.
__global__ __launch_bounds__(256) void initPlus(const float* __restrict__ p,
                                                float* __restrict__ sf,
                                                ushort_t* __restrict__ sh,
                                                ushort_t* __restrict__ ih,
                                                ushort_t* __restrict__ stateT) {
    __shared__ ushort_t trb[128 * 132];
    int tid = threadIdx.x, mt = blockIdx.x;
    size_t base = (size_t)mt * 128 * 128;
#pragma unroll
    for (int rep = 0; rep < 16; ++rep) {
        int idx = rep * 256 + tid, row = idx >> 5, c4 = idx & 31;
        size_t o = base + (size_t)row * 128 + c4 * 4;
        float4 v = *reinterpret_cast<const float4*>(p + o);
        *reinterpret_cast<float4*>(sf + o) = v;
        using u4 = __attribute__((ext_vector_type(4))) unsigned short;
        u4 r; r[0]=f2h(v.x); r[1]=f2h(v.y); r[2]=f2h(v.z); r[3]=f2h(v.w);
        *reinterpret_cast<u4*>(sh + o) = r;
        *reinterpret_cast<u4*>(ih + o) = r;
        trb[row*132 + c4*4 + 0] = r[0]; trb[row*132 + c4*4 + 1] = r[1];
        trb[row*132 + c4*4 + 2] = r[2]; trb[row*132 + c4*4 + 3] = r[3];
    }
    __syncthreads();
    int b = mt >> 2, n0 = (mt & 3) * 128, d = tid >> 1, half = tid & 1;
    ushort_t* dst = stateT + (size_t)b * 65536 + (size_t)d * 512 + n0 + half * 64;
#pragma unroll
    for (int g2 = 0; g2 < 8; ++g2) {
        ushort8 v;
#pragma unroll
        for (int k = 0; k < 8; ++k) v[k] = trb[(half*64 + g2*8 + k)*132 + d];
        *reinterpret_cast<ushort8*>(dst + g2*8) = v;
    }
}

// ---------- step kernels ----------
// aio: a_io[row][out] = sum_e (A_e @ state) @ W_e + sum_e Ars[row][io*4+e]*b_io[e][out]
// Gseg stays in LDS. grid 512 (b,io,nt), 64-row tiles.
__global__ __launch_bounds__(256) void aio_kernel(
    const ushort_t* __restrict__ A_h, const ushort_t* __restrict__ stateT,
    const ushort_t* __restrict__ WstT, const float* __restrict__ Ars,
    const float* __restrict__ in_b, const float* __restrict__ out_b,
    ushort_t* __restrict__ a_in_h, ushort_t* __restrict__ a_out_h) {
    __shared__ char smem[40960] __attribute__((aligned(16)));
    ushort_t* sA     = (ushort_t*)smem;             // [64][64]   8 KB
    ushort_t* sB     = (ushort_t*)(smem + 8192);    // [128][64] 16 KB
    ushort_t* gseg   = (ushort_t*)(smem + 24576);   // [64][128] swz 16 KB
    ushort_t* bounce = (ushort_t*)smem;             // [64][136] 17.4 KB (alias sA+sB)

    int tid = threadIdx.x, w = tid >> 6, l15 = tid & 15, lg = (tid & 63) >> 4;
    int wm = w >> 1, wn = w & 1;
    int bx = blockIdx.x;
    int bid = (bx & 7) * 64 + (bx >> 3);            // XCD swizzle (512 % 8 == 0)
    int nt = bid & 7, io = (bid >> 3) & 1, b = bid >> 4;
    int row0 = b * 512 + nt * 64;

    const ushort_t* Abase = A_h + (size_t)row0 * 4096 + io * 2048;
    const ushort_t* Bst   = stateT + (size_t)b * 65536;
    const ushort_t* Wbase = WstT + io * 65536;

    f32x4 acc_a[2][4]; zaccT(acc_a);
    f32x4 accG[2][4];
#pragma unroll 1
    for (int e = 0; e < 4; ++e) {
        zaccT(accG);
        for (int k0 = 0; k0 < 512; k0 += 64) {
            stage64<64>(Abase + e*512 + k0, 4096, sA, tid);
            stage64<128>(Bst + k0, 512, sB, tid);
            __syncthreads();
            mmaT<64,128,64,false>(sA, 0, sB, accG, wm, wn, l15, lg);
            __syncthreads();
        }
        // accG -> gseg (f16, swizzled)
#pragma unroll
        for (int j = 0; j < 4; ++j) {
            int col = wn*64 + j*16 + l15;
#pragma unroll
            for (int i = 0; i < 2; ++i)
#pragma unroll
                for (int q = 0; q < 4; ++q)
                    st_swz(gseg, wm*32 + i*16 + lg*4 + q, col, f2h(accG[i][j][q]));
        }
        // acc_a += gseg @ W_e   (K=128)
        for (int k0w = 0; k0w < 128; k0w += 64) {
            stage64<128>(Wbase + e*128 + k0w, 512, sB, tid);
            __syncthreads();
            mmaT<64,128,128,true>(gseg, k0w, sB, acc_a, wm, wn, l15, lg);
            __syncthreads();
        }
    }
    // epilogue: bias via rowsums, bounce, coalesced store
    const float* bio = io ? out_b : in_b;
#pragma unroll
    for (int j = 0; j < 4; ++j) {
        int col = wn*64 + j*16 + l15;
        float b0 = bio[col], b1 = bio[128+col], b2 = bio[256+col], b3 = bio[384+col];
#pragma unroll
        for (int i = 0; i < 2; ++i)
#pragma unroll
            for (int q = 0; q < 4; ++q) {
                int row = wm*32 + i*16 + lg*4 + q;
                float4 rsv = *reinterpret_cast<const float4*>(Ars + (size_t)(row0+row)*8 + io*4);
                bounce[row*136 + col] =
                    f2h(acc_a[i][j][q] + rsv.x*b0 + rsv.y*b1 + rsv.z*b2 + rsv.w*b3);
            }
    }
    __syncthreads();
    ushort_t* adst = (io ? a_out_h : a_in_h) + (size_t)row0 * 128;
#pragma unroll
    for (int rep = 0; rep < 4; ++rep) {
        int idx = rep*256 + tid, r = idx >> 4, c8 = idx & 15;
        uint4 v = *reinterpret_cast<uint4*>(bounce + r*136 + c8*8);
        *reinterpret_cast<uint4*>(adst + (size_t)r*128 + c8*8) = v;
    }
}

// rzh: r,z,h gates (K=384 each) + GRU update. grid 512, 32-row tiles, 2 blocks/CU.
__global__ __launch_bounds__(256) void rzh_kernel(
    const ushort_t* __restrict__ a_in_h, const ushort_t* __restrict__ a_out_h,
    const ushort_t* __restrict__ state_h_in,
    const ushort_t* __restrict__ WrzT, const float* __restrict__ rb,
    const float* __restrict__ zb,
    const ushort_t* __restrict__ WtT, const float* __restrict__ tb,
    float* __restrict__ state_f32, ushort_t* __restrict__ state_h,
    ushort_t* __restrict__ stateT) {
    __shared__ char smem[40960] __attribute__((aligned(16)));
    ushort_t* aT  = (ushort_t*)smem;             // 3 x [32][128] swz (a_in, a_out, state->rs)
    ushort_t* sB  = (ushort_t*)(smem + 24576);   // [128][64] 16 KB
    ushort_t* trb = (ushort_t*)smem;             // [32][132] epilogue alias

    int tid = threadIdx.x, w = tid >> 6, l15 = tid & 15, lg = (tid & 63) >> 4;
    int wm = w >> 1, wn = w & 1;
    int row0 = blockIdx.x * 32;

    // reg-stage the 3 A-tiles once, swizzled (reused by all 3 gates)
    const ushort_t* base0 = a_in_h + (size_t)row0*128;
    const ushort_t* base1 = a_out_h + (size_t)row0*128;
    const ushort_t* base2 = state_h_in + (size_t)row0*128;
#pragma unroll
    for (int g0 = 0; g0 < 6; ++g0) {
        int g = g0*256 + tid;
        int T = g >> 9, r = (g >> 4) & 31, c = g & 15;
        const ushort_t* bp = (T == 0) ? base0 : (T == 1) ? base1 : base2;
        uint4 v = *reinterpret_cast<const uint4*>(bp + r*128 + c*8);
        *reinterpret_cast<uint4*>(reinterpret_cast<char*>(aT) + T*8192 + r*256 + ((c ^ (r & 7)) << 4)) = v;
    }

    f32x4 acc[1][4];
#define GSTEP(TS, K0W, BPTR) do {                                          \
        stage64<128>((BPTR), 384, sB, tid);                                \
        __syncthreads();                                                   \
        mmaT<32,128,128,true>(aT + (TS)*4096, (K0W), sB, acc, wm, wn, l15, lg); \
        __syncthreads(); } while (0)

    // ---- r ----
    zaccT(acc);
    GSTEP(0, 0,  WrzT + 0);   GSTEP(0, 64, WrzT + 64);
    GSTEP(1, 0,  WrzT + 128); GSTEP(1, 64, WrzT + 192);
    GSTEP(2, 0,  WrzT + 256); GSTEP(2, 64, WrzT + 320);
    f32x4 rg[4];
#pragma unroll
    for (int j = 0; j < 4; ++j) {
        int col = wn*64 + j*16 + l15;
        float rbv = rb[col];
#pragma unroll
        for (int q = 0; q < 4; ++q) rg[j][q] = sigmoidf_(acc[0][j][q] + rbv);
    }
    // ---- z ----
    zaccT(acc);
    {
        const ushort_t* Wz = WrzT + 128*384;
        GSTEP(0, 0,  Wz + 0);   GSTEP(0, 64, Wz + 64);
        GSTEP(1, 0,  Wz + 128); GSTEP(1, 64, Wz + 192);
        GSTEP(2, 0,  Wz + 256); GSTEP(2, 64, Wz + 320);
    }
    f32x4 zg[4];
#pragma unroll
    for (int j = 0; j < 4; ++j) {
        int col = wn*64 + j*16 + l15;
        float zbv = zb[col];
#pragma unroll
        for (int q = 0; q < 4; ++q) zg[j][q] = sigmoidf_(acc[0][j][q] + zbv);
    }
    // ---- rs = r*s overwrites state tile (z's last use of it is done) ----
#pragma unroll
    for (int j = 0; j < 4; ++j) {
        int col = wn*64 + j*16 + l15;
#pragma unroll
        for (int q = 0; q < 4; ++q) {
            int row = wm*16 + lg*4 + q;
            st_swz(aT + 2*4096, row, col,
                   f2h(rg[j][q] * state_f32[(size_t)(row0+row)*128 + col]));
        }
    }
    // ---- h + update ----
    zaccT(acc);
    GSTEP(0, 0,  WtT + 0);   GSTEP(0, 64, WtT + 64);
    GSTEP(1, 0,  WtT + 128); GSTEP(1, 64, WtT + 192);
    GSTEP(2, 0,  WtT + 256); GSTEP(2, 64, WtT + 320);
#pragma unroll
    for (int j = 0; j < 4; ++j) {
        int col = wn*64 + j*16 + l15;
        float tbv = tb[col];
#pragma unroll
        for (int q = 0; q < 4; ++q) {
            int row = wm*16 + lg*4 + q;
            size_t idx = (size_t)(row0+row)*128 + col;
            float h = tanhf(acc[0][j][q] + tbv);
            float z = zg[j][q];
            float ns = (1.0f - z) * state_f32[idx] + z * h;
            state_f32[idx] = ns;
            trb[row*132 + col] = f2h(ns);
        }
    }
    __syncthreads();
    // coalesced state_h
#pragma unroll
    for (int rep = 0; rep < 2; ++rep) {
        int idx = rep*256 + tid, r = idx >> 4, c8 = idx & 15;
        ushort8 v;
#pragma unroll
        for (int k = 0; k < 8; ++k) v[k] = trb[r*132 + c8*8 + k];
        *reinterpret_cast<ushort8*>(state_h + (size_t)(row0+r)*128 + c8*8) = v;
    }
    // stateT transpose-out
    {
        int b = row0 >> 9, n0 = row0 & 511, d = tid >> 1, half = tid & 1;
        ushort_t* dst = stateT + (size_t)b*65536 + (size_t)d*512 + n0 + half*16;
#pragma unroll
        for (int g2 = 0; g2 < 2; ++g2) {
            ushort8 v;
#pragma unroll
            for (int k = 0; k < 8; ++k) v[k] = trb[(half*16 + g2*8 + k)*132 + d];
            *reinterpret_cast<ushort8*>(dst + g2*8) = v;
        }
    }
#undef GSTEP
}

// final: out = tanh([state|init] @ oW + ob)  (K=256)
__global__ __launch_bounds__(256) void final_kernel(const ushort_t* __restrict__ state_h,
                                                    const ushort_t* __restrict__ init_h,
                                                    const ushort_t* __restrict__ WoT,
                                                    const float* __restrict__ ob,
                                                    float* __restrict__ out) {
    __shared__ alignas(16) ushort_t lA[128*64];
    __shared__ alignas(16) ushort_t lB[128*64];
    int tid = threadIdx.x, w = tid >> 6, l15 = tid & 15, lg = (tid & 63) >> 4;
    int wm = w >> 1, wn = w & 1;
    int mt = blockIdx.x;

    const ushort_t* srcs[2] = { state_h + (size_t)mt*128*128,
                                init_h + (size_t)mt*128*128 };
    f32x4 acc[4][4] = {};
    for (int k0 = 0; k0 < 256; k0 += 64) {
        stage64<128>(srcs[k0 >> 7] + (k0 & 127), 128, lA, tid);
        stage64<128>(WoT + k0, 256, lB, tid);
        __syncthreads();
        mmaT<128, 128, 64, false>(lA, 0, lB, acc, wm, wn, l15, lg);
        __syncthreads();
    }
#pragma unroll
    for (int j = 0; j < 4; ++j) {
        int col = wn*64 + j*16 + l15;
        float bv = ob[col];
#pragma unroll
        for (int i = 0; i < 4; ++i)
#pragma unroll
            for (int q = 0; q < 4; ++q) {
                int row = mt*128 + wm*64 + i*16 + lg*4 + q;
                out[(size_t)row * 128 + col] = tanhf(acc[i][j][q] + bv);
            }
    }
}

// ---------- launch ----------
extern "C" void kernel_launch(void* const* d_in, const int* in_sizes, int n_in,
                              void* d_out, int out_size, void* d_ws, size_t ws_size,
                              hipStream_t stream) {
    const float* prop  = (const float*)d_in[0];
    const float* A     = (const float*)d_in[1];
    const float* in_W  = (const float*)d_in[3];
    const float* in_b  = (const float*)d_in[4];
    const float* out_W = (const float*)d_in[5];
    const float* out_b = (const float*)d_in[6];
    const float* rW    = (const float*)d_in[7];
    const float* rb    = (const float*)d_in[8];
    const float* zW    = (const float*)d_in[9];
    const float* zb    = (const float*)d_in[10];
    const float* tW    = (const float*)d_in[11];
    const float* tb    = (const float*)d_in[12];
    const float* oW    = (const float*)d_in[13];
    const float* ob    = (const float*)d_in[14];
    float* outp = (float*)d_out;

    size_t off = 0;
    auto carve = [&](size_t bytes) {
        void* p = (char*)d_ws + off;
        off += (bytes + 255) & ~(size_t)255;
        return p;
    };
    ushort_t* A_h      = (ushort_t*)carve((size_t)M_TOT*4096*2);   // 134 MB
    ushort_t* stateT   = (ushort_t*)carve((size_t)B_*D_*N_*2);     // 4.2 MB
    ushort_t* a_in_h   = (ushort_t*)carve((size_t)M_TOT*D_*2);
    ushort_t* a_out_h  = (ushort_t*)carve((size_t)M_TOT*D_*2);
    ushort_t* state_h  = (ushort_t*)carve((size_t)M_TOT*D_*2);
    ushort_t* init_h   = (ushort_t*)carve((size_t)M_TOT*D_*2);
    float*    state_f32= (float*)carve((size_t)M_TOT*D_*4);
    float*    Ars      = (float*)carve((size_t)M_TOT*8*4);
    ushort_t* WstT     = (ushort_t*)carve((size_t)2*128*512*2);
    ushort_t* WrzT     = (ushort_t*)carve((size_t)256*384*2);
    ushort_t* WtT      = (ushort_t*)carve((size_t)128*384*2);
    ushort_t* WoT      = (ushort_t*)carve((size_t)128*256*2);
    (void)ws_size; (void)n_in; (void)in_sizes; (void)out_size;

    convertA_rs<<<16384, 256, 0, stream>>>(A, A_h, Ars);
    prep_weights<<<1216, 256, 0, stream>>>(in_W, out_W, rW, zW, tW, oW, WstT, WrzT, WtT, WoT);
    initPlus<<<128, 256, 0, stream>>>(prop, state_f32, state_h, init_h, stateT);

    for (int s = 0; s < STEPS_; ++s) {
        aio_kernel<<<512, 256, 0, stream>>>(A_h, stateT, WstT, Ars, in_b, out_b,
                                            a_in_h, a_out_h);
        rzh_kernel<<<512, 256, 0, stream>>>(a_in_h, a_out_h, state_h,
                                            WrzT, rb, zb, WtT, tb,
                                            state_f32, state_h, stateT);
    }
    final_kernel<<<128, 256, 0, stream>>>(state_h, init_h, WoT, ob, outp);
}